// Round 8
// baseline (693.186 us; speedup 1.0000x reference)
//
#include <hip/hip_runtime.h>

#define NN 50000
#define NE 800000
#define NH 64
#define NG 500
#define NPAD 50176   // 196*256
#define NBKT 782     // ceil(NN/64) 64-node buckets
#define CAP 1536     // padded bucket capacity (max bucket deg ~1130; 4.5+ sigma margin)
#define ZR NN        // dedicated zero row in hWbf (zeroed once in k_prep)
#define SH 25088     // src shard split: shard0 = src < SH (3.2 MB of hWbf rows, fits 4 MB XCD L2)
#define NBLK 1024    // persistent gather grid: 4 blocks/CU x 256 CU, guaranteed by launch_bounds(256,4)
#define NPW 13       // nodes per wave: 1024 blk x 4 waves x 13 = 53248 >= NN

typedef __attribute__((ext_vector_type(8))) short bf16x8;   // 8 bf16 = 4 VGPR (MFMA A/B frag)
typedef __attribute__((ext_vector_type(4))) float f32x4;    // MFMA C/D frag

// fp32 -> bf16 round-to-nearest-even
__device__ __forceinline__ unsigned short f2bf(float f) {
  unsigned x = __float_as_uint(f);
  unsigned r = ((x >> 16) & 1u) + 0x7fffu;
  return (unsigned short)((x + r) >> 16);
}
__device__ __forceinline__ float bf2f(unsigned short u) {
  return __uint_as_float(((unsigned)u) << 16);
}

// ---------------- prep: W fragments + zero bcur (incl. barrier slots) / ZR-row ----------------
// Wf fragment convention (16x16x32 bf16): lane = (idx&15) + 16*kb; element e <-> k = s*32 + kb*8 + e.
// fid = mat*16 + part*8 + s*4 + ntile; mat: 0=conv 1=res; part: 0=bf16-hi 1=bf16-lo.

__global__ __launch_bounds__(256) void k_prep(const float* __restrict__ Wc, const float* __restrict__ Wr,
                                              unsigned short* __restrict__ Wf,
                                              int* __restrict__ bcur,
                                              unsigned short* __restrict__ hWbf) {
  if (blockIdx.x == 8) {
    int tt = threadIdx.x;
    for (int i = tt; i < 1024; i += 256) bcur[i] = 0;   // buckets + barrier cnt/gen
    if (tt < 32) ((unsigned*)(hWbf + (size_t)ZR * 64))[tt] = 0u;
    return;
  }
  int t = blockIdx.x * 256 + threadIdx.x;   // 2048 threads = 32 frags * 64 lanes
  int fid = t >> 6;
  int lane = t & 63;
  int ntile = fid & 3, s = (fid >> 2) & 1, part = (fid >> 3) & 1, mat = fid >> 4;
  const float* W = mat ? Wr : Wc;
  int col = ntile * 16 + (lane & 15);
  int k0 = s * 32 + (lane >> 4) * 8;
#pragma unroll
  for (int e = 0; e < 8; e++) {
    float w = W[(k0 + e) * 64 + col];
    unsigned short h = f2bf(w);
    Wf[(size_t)fid * 512 + lane * 8 + e] = part ? f2bf(w - bf2f(h)) : h;
  }
}

// ---------------- binning into padded buckets: colp[b*CAP + r] ----------------

__global__ __launch_bounds__(256) void k_bin(const int* __restrict__ src, const int* __restrict__ dst,
                                             int* __restrict__ bcur, int* __restrict__ colp) {
  __shared__ int hist[NBKT];
  __shared__ int gbase[NBKT];
  int t = threadIdx.x;
  for (int b = t; b < NBKT; b += 256) hist[b] = 0;
  __syncthreads();
  int e0 = blockIdx.x * 8192;
#pragma unroll
  for (int i = 0; i < 32; i++) {
    int e = e0 + i * 256 + t;
    if (e < NE) atomicAdd(&hist[dst[e] >> 6], 1);
  }
  __syncthreads();
  for (int b = t; b < NBKT; b += 256) {
    int c = hist[b];
    gbase[b] = c ? atomicAdd(&bcur[b], c) : 0;
    hist[b] = 0;  // reuse as rank counter
  }
  __syncthreads();
#pragma unroll
  for (int i = 0; i < 32; i++) {
    int e = e0 + i * 256 + t;
    if (e < NE) {
      int s = src[e], d = dst[e];
      int b = d >> 6;
      int r = atomicAdd(&hist[b], 1);
      colp[b * CAP + gbase[b] + r] = (s << 6) | (d & 63);
    }
  }
}

// ---------------- shared gemm tile body (MFMA, LDS-free, split-bf16) ----------------
// MODE 0: X = Xin. MODE 1: X = relu(Xin + dinv[n]*bf2f(gsum[n])).

template <int MODE>
__device__ __forceinline__ void gemm_tile(int lane, int n0,
                                          const float* __restrict__ Xin,
                                          const unsigned short* __restrict__ gsum,
                                          const unsigned short* __restrict__ Wf,
                                          const float* __restrict__ cb, const float* __restrict__ rb,
                                          const float* __restrict__ dinv,
                                          unsigned short* __restrict__ hWout, float* __restrict__ agg) {
  int col16 = lane & 15;
  int kb = lane >> 4;
  int nr = n0 + col16;
  int nc = nr < NN ? nr : NN - 1;   // clamp loads; garbage rows never stored
  const float* xrow = Xin + (size_t)nc * 64;
  float v0[8], v1[8];
  {
    float4 a = *(const float4*)(xrow + kb * 8);
    float4 b4 = *(const float4*)(xrow + kb * 8 + 4);
    float4 c = *(const float4*)(xrow + 32 + kb * 8);
    float4 d = *(const float4*)(xrow + 32 + kb * 8 + 4);
    v0[0] = a.x; v0[1] = a.y; v0[2] = a.z; v0[3] = a.w;
    v0[4] = b4.x; v0[5] = b4.y; v0[6] = b4.z; v0[7] = b4.w;
    v1[0] = c.x; v1[1] = c.y; v1[2] = c.z; v1[3] = c.w;
    v1[4] = d.x; v1[5] = d.y; v1[6] = d.z; v1[7] = d.w;
  }
  if (MODE) {
    float dvn = dinv[nc];
    const unsigned* grow = (const unsigned*)(gsum + (size_t)nc * 64);
    uint4 g0 = *(const uint4*)(grow + kb * 4);
    uint4 g1 = *(const uint4*)(grow + 16 + kb * 4);
    unsigned ga[4] = {g0.x, g0.y, g0.z, g0.w};
    unsigned gb[4] = {g1.x, g1.y, g1.z, g1.w};
#pragma unroll
    for (int e = 0; e < 4; e++) {
      v0[2 * e]     = fmaxf(v0[2 * e]     + dvn * bf2f((unsigned short)(ga[e] & 0xffff)), 0.f);
      v0[2 * e + 1] = fmaxf(v0[2 * e + 1] + dvn * bf2f((unsigned short)(ga[e] >> 16)), 0.f);
      v1[2 * e]     = fmaxf(v1[2 * e]     + dvn * bf2f((unsigned short)(gb[e] & 0xffff)), 0.f);
      v1[2 * e + 1] = fmaxf(v1[2 * e + 1] + dvn * bf2f((unsigned short)(gb[e] >> 16)), 0.f);
    }
  }
  bf16x8 ah0, al0, ah1, al1;
#pragma unroll
  for (int e = 0; e < 8; e++) {
    unsigned short h0 = f2bf(v0[e]);
    ah0[e] = (short)h0;
    al0[e] = (short)f2bf(v0[e] - bf2f(h0));
    unsigned short h1 = f2bf(v1[e]);
    ah1[e] = (short)h1;
    al1[e] = (short)f2bf(v1[e] - bf2f(h1));
  }

  f32x4 aC[4], aR[4];
#pragma unroll
  for (int j = 0; j < 4; j++) {
    aC[j] = (f32x4){0.f, 0.f, 0.f, 0.f};
    aR[j] = (f32x4){0.f, 0.f, 0.f, 0.f};
  }
  const bf16x8* WFv = (const bf16x8*)Wf;
#pragma unroll
  for (int j = 0; j < 4; j++) {
    bf16x8 wch0 = WFv[(j)      * 64 + lane];
    bf16x8 wch1 = WFv[(4 + j)  * 64 + lane];
    bf16x8 wcl0 = WFv[(8 + j)  * 64 + lane];
    bf16x8 wcl1 = WFv[(12 + j) * 64 + lane];
    bf16x8 wrh0 = WFv[(16 + j) * 64 + lane];
    bf16x8 wrh1 = WFv[(20 + j) * 64 + lane];
    bf16x8 wrl0 = WFv[(24 + j) * 64 + lane];
    bf16x8 wrl1 = WFv[(28 + j) * 64 + lane];
    f32x4 c = aC[j];
    c = __builtin_amdgcn_mfma_f32_16x16x32_bf16(ah0, wch0, c, 0, 0, 0);
    c = __builtin_amdgcn_mfma_f32_16x16x32_bf16(ah1, wch1, c, 0, 0, 0);
    c = __builtin_amdgcn_mfma_f32_16x16x32_bf16(al0, wch0, c, 0, 0, 0);
    c = __builtin_amdgcn_mfma_f32_16x16x32_bf16(al1, wch1, c, 0, 0, 0);
    c = __builtin_amdgcn_mfma_f32_16x16x32_bf16(ah0, wcl0, c, 0, 0, 0);
    c = __builtin_amdgcn_mfma_f32_16x16x32_bf16(ah1, wcl1, c, 0, 0, 0);
    aC[j] = c;
    f32x4 r = aR[j];
    r = __builtin_amdgcn_mfma_f32_16x16x32_bf16(ah0, wrh0, r, 0, 0, 0);
    r = __builtin_amdgcn_mfma_f32_16x16x32_bf16(ah1, wrh1, r, 0, 0, 0);
    r = __builtin_amdgcn_mfma_f32_16x16x32_bf16(al0, wrh0, r, 0, 0, 0);
    r = __builtin_amdgcn_mfma_f32_16x16x32_bf16(al1, wrh1, r, 0, 0, 0);
    r = __builtin_amdgcn_mfma_f32_16x16x32_bf16(ah0, wrl0, r, 0, 0, 0);
    r = __builtin_amdgcn_mfma_f32_16x16x32_bf16(ah1, wrl1, r, 0, 0, 0);
    aR[j] = r;
  }

  // epilogue: D layout col=lane&15, row=(lane>>4)*4+reg
  float cbv[4], rbv[4];
#pragma unroll
  for (int j = 0; j < 4; j++) {
    cbv[j] = cb[j * 16 + col16];
    rbv[j] = rb[j * 16 + col16];
  }
  int rbase = kb * 4;
#pragma unroll
  for (int r = 0; r < 4; r++) {
    int node = n0 + rbase + r;
    if (node < NN) {
      float dv = dinv[node];
      size_t o = (size_t)node * 64 + col16;
#pragma unroll
      for (int j = 0; j < 4; j++) {
        float hc = dv * aC[j][r];
        unsigned short hb = f2bf(hc);
        hWout[o + j * 16] = hb;
        agg[o + j * 16] = aR[j][r] + rbv[j] + cbv[j] + dv * hc;
      }
    }
  }
}

// ---------------- fused: bucket CSR (src-sharded rows) + gptr + encoder + gemm0 ----------------
// Each row's cols list is split: [st, mid) = src<SH, [mid, en) = src>=SH.

__global__ __launch_bounds__(256) void k_csr_enc_g0(const int* __restrict__ bcur, const int* __restrict__ colp,
                                                    int* __restrict__ cols, float* __restrict__ dinv,
                                                    int2* __restrict__ rows2, int* __restrict__ midg,
                                                    const int* __restrict__ batch, int* __restrict__ gptr,
                                                    const float* __restrict__ x, const float* __restrict__ pos,
                                                    const float* __restrict__ encW, const float* __restrict__ encb,
                                                    const unsigned short* __restrict__ Wf,
                                                    const float* __restrict__ cb, const float* __restrict__ rb,
                                                    unsigned short* __restrict__ hWout,
                                                    float* __restrict__ X0, float* __restrict__ agg) {
  __shared__ int h0c[64], h1c[64];
  __shared__ int excl[65];
  __shared__ int midS[64];
  __shared__ float Ws[16 * 64];
  __shared__ float bs[64];
  int t = threadIdx.x;
  int b = blockIdx.x;

  // folded gptr: graph segment pointers from sorted batch (independent work)
  int tid = b * 256 + t;
  if (tid < NN) {
    int bi = batch[tid];
    int bp = (tid > 0) ? batch[tid - 1] : -1;
    for (int g = bp + 1; g <= bi; g++) gptr[g] = tid;
    if (tid == NN - 1) {
      for (int g = bi + 1; g <= NG; g++) gptr[g] = NN;
    }
  }

  for (int i = t; i < 1024; i += 256) Ws[i] = encW[i];
  if (t < 64) bs[t] = encb[t];

  int base = b * CAP;
  int cnt = bcur[b];
  if (t < 64) { h0c[t] = 0; h1c[t] = 0; }
  __syncthreads();
  for (int e = t; e < cnt; e += 256) {
    int w = colp[base + e];
    if ((w >> 6) < SH) atomicAdd(&h0c[w & 63], 1); else atomicAdd(&h1c[w & 63], 1);
  }
  __syncthreads();
  if (t == 0) {
    int run = 0;
#pragma unroll
    for (int i = 0; i < 64; i++) { excl[i] = run; run += h0c[i] + h1c[i]; }
    excl[64] = run;
  }
  __syncthreads();
  if (t < 64) {
    int n = b * 64 + t;
    rows2[n] = make_int2(base + excl[t], base + excl[t + 1]);
    int m = excl[t] + h0c[t];
    midS[t] = m;
    midg[n] = base + m;
    if (n < NN) dinv[n] = rsqrtf((float)(h0c[t] + h1c[t] + 1));  // +1 self-loop
  }
  __syncthreads();
  if (t < 64) { h0c[t] = 0; h1c[t] = 0; }  // reuse as cursors
  __syncthreads();
  for (int e = t; e < cnt; e += 256) {
    int w = colp[base + e];
    int d = w & 63, s = w >> 6;
    if (s < SH) {
      int r = atomicAdd(&h0c[d], 1);
      cols[base + excl[d] + r] = s;
    } else {
      int r = atomicAdd(&h1c[d], 1);
      cols[base + midS[d] + r] = s;
    }
  }

  // encoder for this bucket's 64 rows (disjoint from cols scatter; barrier below covers both)
  int h = t & 63;
  int nset = t >> 6;
#pragma unroll
  for (int i = 0; i < 16; i++) {
    int n = b * 64 + nset * 16 + i;
    if (n < NN) {
      const float* xr = x + n * 14;
      float acc = bs[h];
#pragma unroll
      for (int f = 0; f < 14; f++) acc += xr[f] * Ws[f * 64 + h];
      acc += pos[n * 2 + 0] * Ws[14 * 64 + h];
      acc += pos[n * 2 + 1] * Ws[15 * 64 + h];
      X0[(size_t)n * 64 + h] = acc;
    }
  }
  __syncthreads();  // X0 + dinv visible block-wide (same CU)

  // gemm0 (mode 0): 4 waves x 16 rows x 64 cols
  gemm_tile<0>(t & 63, b * 64 + (t >> 6) * 16, X0, (const unsigned short*)0, Wf, cb, rb, dinv, hWout, agg);
}

// ---------------- standalone gemm (mode 1), layers 1..4 ----------------

__global__ __launch_bounds__(256) void k_gemm(const float* __restrict__ Xin,
                                              const unsigned short* __restrict__ gsum,
                                              const unsigned short* __restrict__ Wf,
                                              const float* __restrict__ cb, const float* __restrict__ rb,
                                              const float* __restrict__ dinv,
                                              unsigned short* __restrict__ hWout, float* __restrict__ agg) {
  gemm_tile<1>(threadIdx.x & 63, blockIdx.x * 64 + (threadIdx.x >> 6) * 16,
               Xin, gsum, Wf, cb, rb, dinv, hWout, agg);
}

// ---------------- gather segment core (R5-proven): 8 loads in flight, nt cols ----------------
// lane = (p = lane>>5, h2 = lane&31): h-pair 2*h2, 2*h2+1 of edge-pair-member p. Full 128 B rows.
// cols loads are nontemporal so the streamed index array doesn't evict the hW table shard.

__device__ __forceinline__ void gather_seg(int st, int en, int lane, int h2, int p,
                                           const int* __restrict__ cols, const unsigned* __restrict__ hW32,
                                           float& a0, float& a1) {
  int deg = en - st;
  a0 = 0.f; a1 = 0.f;
  for (int base2 = 0; base2 < deg; base2 += 64) {
    int cnt = deg - base2;
    if (cnt > 64) cnt = 64;
    int li = lane < cnt ? lane : cnt - 1;
    int colv = __builtin_nontemporal_load(cols + st + base2 + li);
    for (int j = 0; j < cnt; j += 16) {
      int sx[8];
#pragma unroll
      for (int k2 = 0; k2 < 8; k2++) {
        int e = j + 2 * k2 + p;
        int s = __shfl(colv, e, 64);
        sx[k2] = e < cnt ? s : ZR;   // padding -> dedicated zero row (one hot line)
      }
      unsigned ux[8];
#pragma unroll
      for (int k2 = 0; k2 < 8; k2++) ux[k2] = hW32[(unsigned)sx[k2] * 32u + (unsigned)h2];
#pragma unroll
      for (int k2 = 0; k2 < 8; k2++) {
        a0 += __uint_as_float(ux[k2] << 16);
        a1 += __uint_as_float(ux[k2] & 0xffff0000u);
      }
    }
  }
  a0 += __shfl_down(a0, 32, 64);
  a1 += __shfl_down(a1, 32, 64);
}

// ---------------- persistent 2-phase gather: shard0 -> LDS partials -> grid barrier -> shard1 ----------------
// 1024 blocks = 4/CU guaranteed resident ((256,4), 13KB LDS). The barrier carries NO data
// (partials stay in LDS) - it is purely a performance fence keeping each phase's random reads
// inside one 3.2 MB L2-resident shard. last=1: fuse decode -> Xo instead of gsum write.

__global__ __launch_bounds__(256, 4) void k_gather2(const int2* __restrict__ rows2, const int* __restrict__ midg,
                                                    const int* __restrict__ cols,
                                                    const unsigned short* __restrict__ hWin,
                                                    unsigned short* __restrict__ gsum,
                                                    const float* __restrict__ aggIn, const float* __restrict__ dinv,
                                                    const float* __restrict__ decW, float* __restrict__ Xo,
                                                    int* __restrict__ bar_cnt, volatile int* bar_gen, int last) {
  __shared__ float pA[2][4][NPW][32];   // 13312 B: [a0/a1][wave][node][h2]
  int t = threadIdx.x;
  int lane = t & 63, h2 = lane & 31, p = lane >> 5, wv = t >> 6;
  int nb = (blockIdx.x * 4 + wv) * NPW;
  const unsigned* hW32 = (const unsigned*)hWin;

  // phase A: shard 0 (src < SH)
#pragma unroll 1
  for (int i = 0; i < NPW; i++) {
    int n = nb + i;
    if (n < NN) {
      float a0, a1;
      gather_seg(rows2[n].x, midg[n], lane, h2, p, cols, hW32, a0, a1);
      if (lane < 32) { pA[0][wv][i][h2] = a0; pA[1][wv][i][h2] = a1; }
    }
  }

  // grid barrier (perf-only; all NBLK blocks co-resident by construction)
  __syncthreads();
  if (t == 0) {
    int g = *bar_gen;
    int v = atomicAdd(bar_cnt, 1);
    if (v == NBLK - 1) {
      *bar_cnt = 0;
      __threadfence();
      atomicAdd((int*)bar_gen, 1);
    } else {
      while (*bar_gen == g) __builtin_amdgcn_s_sleep(16);
    }
  }
  __syncthreads();

  // phase B: shard 1 (src >= SH) + combine + output
#pragma unroll 1
  for (int i = 0; i < NPW; i++) {
    int n = nb + i;
    if (n < NN) {
      float a0, a1;
      gather_seg(midg[n], rows2[n].y, lane, h2, p, cols, hW32, a0, a1);
      a0 += pA[0][wv][i][h2];   // lanes>=32 read lane h2's value; discarded below
      a1 += pA[1][wv][i][h2];
      if (!last) {
        if (lane < 32)
          __builtin_nontemporal_store((unsigned)f2bf(a0) | ((unsigned)f2bf(a1) << 16),
                                      (unsigned*)gsum + (size_t)n * 32 + h2);
      } else {
        float dv = dinv[n];
        float2 ag;
        ag.x = __builtin_nontemporal_load(aggIn + (size_t)n * 64 + h2 * 2);
        ag.y = __builtin_nontemporal_load(aggIn + (size_t)n * 64 + h2 * 2 + 1);
        float v = fmaxf(ag.x + dv * a0, 0.f) * decW[h2 * 2] + fmaxf(ag.y + dv * a1, 0.f) * decW[h2 * 2 + 1];
        v = (lane < 32) ? v : 0.f;
#pragma unroll
        for (int off = 32; off > 0; off >>= 1) v += __shfl_down(v, off, 64);
        if (lane == 0) Xo[n] = v;
      }
    }
  }
}

// ---------------- graph pooling: out[g] = sum Xo[gptr[g]:gptr[g+1]] + cnt*decb ----------------

__global__ __launch_bounds__(256) void k_pool(const float* __restrict__ Xo, const int* __restrict__ gptr,
                                              const float* __restrict__ decb, float* __restrict__ out) {
  __shared__ float part[4];
  int g = blockIdx.x;
  int t = threadIdx.x;
  int st = gptr[g], en = gptr[g + 1];
  float v = 0.f;
  for (int i = st + t; i < en; i += 256) v += Xo[i];
#pragma unroll
  for (int off = 32; off > 0; off >>= 1) v += __shfl_down(v, off, 64);
  if ((t & 63) == 0) part[t >> 6] = v;
  __syncthreads();
  if (t == 0) out[g] = part[0] + part[1] + part[2] + part[3] + (float)(en - st) * decb[0];
}

// ---------------- launch: 13 dispatches ----------------

extern "C" void kernel_launch(void* const* d_in, const int* in_sizes, int n_in,
                              void* d_out, int out_size, void* d_ws, size_t ws_size,
                              hipStream_t stream) {
  (void)in_sizes; (void)n_in; (void)out_size; (void)ws_size;
  const float* x     = (const float*)d_in[0];
  const float* pos   = (const float*)d_in[1];
  const int*   ei    = (const int*)d_in[2];
  const int*   batch = (const int*)d_in[3];
  const float* encW  = (const float*)d_in[4];
  const float* encb  = (const float*)d_in[5];
  const float* convW = (const float*)d_in[6];
  const float* convb = (const float*)d_in[7];
  const float* resW  = (const float*)d_in[8];
  const float* resb  = (const float*)d_in[9];
  const float* decW  = (const float*)d_in[10];
  const float* decb  = (const float*)d_in[11];
  float* out = (float*)d_out;

  const int* src = ei;       // edge_index[0]
  const int* dst = ei + NE;  // edge_index[1]

  // workspace layout (4-byte elems)
  float*          ws    = (float*)d_ws;
  float*          dinv  = ws;                                    // [NPAD]
  int2*           rows2 = (int2*)(ws + NPAD);                    // [NPAD] {st,en}
  int*            midg  = (int*)(ws + 3 * NPAD);                 // [NPAD] shard split point
  int*            bcur  = (int*)(ws + 4 * NPAD);                 // [1024] buckets + barrier slots
  int*            gptr  = bcur + 1024;                           // [NG+1]
  float*          Xo    = (float*)(gptr + 512);                  // [NPAD]
  int*            colp  = (int*)(Xo + NPAD);                     // [NBKT*CAP]
  int*            cols  = colp + NBKT * CAP;                     // [NBKT*CAP]
  unsigned short* hWbf  = (unsigned short*)(cols + NBKT * CAP);  // [NPAD*64] bf16
  unsigned short* gsum  = hWbf + (size_t)NPAD * 64;              // [NPAD*64] bf16
  float*          bufA  = (float*)(gsum + (size_t)NPAD * 64);    // [NN*NH]
  float*          bufB  = bufA + NN * NH;                        // [NN*NH]
  unsigned short* Wf    = (unsigned short*)(bufB + NN * NH);     // [32*512] bf16 frag W

  int* bar_cnt = bcur + 800;           // zeroed by k_prep
  volatile int* bar_gen = (volatile int*)(bcur + 801);

  k_prep<<<9, 256, 0, stream>>>(convW, resW, Wf, bcur, hWbf);
  k_bin<<<(NE + 8191) / 8192, 256, 0, stream>>>(src, dst, bcur, colp);
  k_csr_enc_g0<<<NBKT, 256, 0, stream>>>(bcur, colp, cols, dinv, rows2, midg, batch, gptr,
                                         x, pos, encW, encb, Wf, convb, resb,
                                         hWbf, bufA, bufB);
  // layers: persistent 2-phase gather -> gsum; gemm mode1 -> hW_{l+1}; agg ping-pong
  float* aggIn = bufB;
  float* aggOut = bufA;
  for (int l = 0; l < 4; l++) {
    k_gather2<<<NBLK, 256, 0, stream>>>(rows2, midg, cols, hWbf, gsum,
                                        (const float*)0, dinv, decW, (float*)0, bar_cnt, bar_gen, 0);
    k_gemm<<<NBKT, 256, 0, stream>>>(aggIn, gsum, Wf, convb, resb, dinv, hWbf, aggOut);
    float* tmp = aggIn; aggIn = aggOut; aggOut = tmp;
  }
  k_gather2<<<NBLK, 256, 0, stream>>>(rows2, midg, cols, hWbf, gsum,
                                      aggIn, dinv, decW, Xo, bar_cnt, bar_gen, 1);
  k_pool<<<NG, 256, 0, stream>>>(Xo, gptr, decb, out);
}

// Round 9
// 316.600 us; speedup vs baseline: 2.1895x; 2.1895x over previous
//
#include <hip/hip_runtime.h>

#define NN 50000
#define NE 800000
#define NH 64
#define NG 500
#define NPAD 50176   // 196*256
#define NBKT 782     // ceil(NN/64) 64-node buckets
#define CAP 1536     // padded bucket capacity (max bucket deg ~1130; 4.5+ sigma margin)
#define ZR NN        // dedicated zero row per half-table (zeroed once in k_prep)
#define NBH 12500    // NN/4 node-groups; gather grid = 2*NBH interleaved halves

typedef __attribute__((ext_vector_type(8))) short bf16x8;   // 8 bf16 = 4 VGPR (MFMA A/B frag)
typedef __attribute__((ext_vector_type(4))) float f32x4;    // MFMA C/D frag

// fp32 -> bf16 round-to-nearest-even
__device__ __forceinline__ unsigned short f2bf(float f) {
  unsigned x = __float_as_uint(f);
  unsigned r = ((x >> 16) & 1u) + 0x7fffu;
  return (unsigned short)((x + r) >> 16);
}
__device__ __forceinline__ float bf2f(unsigned short u) {
  return __uint_as_float(((unsigned)u) << 16);
}

// ---------------- prep: W fragments + zero bcur/ZR half-rows ----------------
// hWbf layout h-SPLIT: [half][node][32 h] bf16 (64 B half-rows). Gather blocks are XCD-pinned
// to one half (half = blockIdx&1, round-robin blockIdx->XCD) so each XCD's L2 pulls only its
// 3.2 MB half-table: compulsory per-XCD replication fill (the R8-measured floor) is halved.
// Wf fragment convention (16x16x32 bf16): lane = (idx&15) + 16*kb; element e <-> k = s*32 + kb*8 + e.
// fid = mat*16 + part*8 + s*4 + ntile; mat: 0=conv 1=res; part: 0=bf16-hi 1=bf16-lo.

__global__ __launch_bounds__(256) void k_prep(const float* __restrict__ Wc, const float* __restrict__ Wr,
                                              unsigned short* __restrict__ Wf,
                                              int* __restrict__ bcur,
                                              unsigned short* __restrict__ hWbf) {
  if (blockIdx.x == 8) {
    int tt = threadIdx.x;
    for (int i = tt; i < 1024; i += 256) bcur[i] = 0;
    if (tt < 16) {
      ((unsigned*)hWbf)[((size_t)(0 * NPAD + ZR)) * 16 + tt] = 0u;
      ((unsigned*)hWbf)[((size_t)(1 * NPAD + ZR)) * 16 + tt] = 0u;
    }
    return;
  }
  int t = blockIdx.x * 256 + threadIdx.x;   // 2048 threads = 32 frags * 64 lanes
  int fid = t >> 6;
  int lane = t & 63;
  int ntile = fid & 3, s = (fid >> 2) & 1, part = (fid >> 3) & 1, mat = fid >> 4;
  const float* W = mat ? Wr : Wc;
  int col = ntile * 16 + (lane & 15);
  int k0 = s * 32 + (lane >> 4) * 8;
#pragma unroll
  for (int e = 0; e < 8; e++) {
    float w = W[(k0 + e) * 64 + col];
    unsigned short h = f2bf(w);
    Wf[(size_t)fid * 512 + lane * 8 + e] = part ? f2bf(w - bf2f(h)) : h;
  }
}

// ---------------- binning into padded buckets: colp[b*CAP + r] ----------------

__global__ __launch_bounds__(256) void k_bin(const int* __restrict__ src, const int* __restrict__ dst,
                                             int* __restrict__ bcur, int* __restrict__ colp) {
  __shared__ int hist[NBKT];
  __shared__ int gbase[NBKT];
  int t = threadIdx.x;
  for (int b = t; b < NBKT; b += 256) hist[b] = 0;
  __syncthreads();
  int e0 = blockIdx.x * 8192;
#pragma unroll
  for (int i = 0; i < 32; i++) {
    int e = e0 + i * 256 + t;
    if (e < NE) atomicAdd(&hist[dst[e] >> 6], 1);
  }
  __syncthreads();
  for (int b = t; b < NBKT; b += 256) {
    int c = hist[b];
    gbase[b] = c ? atomicAdd(&bcur[b], c) : 0;
    hist[b] = 0;  // reuse as rank counter
  }
  __syncthreads();
#pragma unroll
  for (int i = 0; i < 32; i++) {
    int e = e0 + i * 256 + t;
    if (e < NE) {
      int s = src[e], d = dst[e];
      int b = d >> 6;
      int r = atomicAdd(&hist[b], 1);
      colp[b * CAP + gbase[b] + r] = (s << 6) | (d & 63);
    }
  }
}

// ---------------- shared gemm tile body (MFMA, LDS-free, split-bf16) ----------------
// MODE 0: X = Xin. MODE 1: X = relu(Xin + dinv[n]*bf2f(gsum[n])).
// hW write goes to the h-split layout: [half=j>>1][node][(j&1)*16 + col16].

template <int MODE>
__device__ __forceinline__ void gemm_tile(int lane, int n0,
                                          const float* __restrict__ Xin,
                                          const unsigned short* __restrict__ gsum,
                                          const unsigned short* __restrict__ Wf,
                                          const float* __restrict__ cb, const float* __restrict__ rb,
                                          const float* __restrict__ dinv,
                                          unsigned short* __restrict__ hWout, float* __restrict__ agg) {
  int col16 = lane & 15;
  int kb = lane >> 4;
  int nr = n0 + col16;
  int nc = nr < NN ? nr : NN - 1;   // clamp loads; garbage rows never stored
  const float* xrow = Xin + (size_t)nc * 64;
  float v0[8], v1[8];
  {
    float4 a = *(const float4*)(xrow + kb * 8);
    float4 b4 = *(const float4*)(xrow + kb * 8 + 4);
    float4 c = *(const float4*)(xrow + 32 + kb * 8);
    float4 d = *(const float4*)(xrow + 32 + kb * 8 + 4);
    v0[0] = a.x; v0[1] = a.y; v0[2] = a.z; v0[3] = a.w;
    v0[4] = b4.x; v0[5] = b4.y; v0[6] = b4.z; v0[7] = b4.w;
    v1[0] = c.x; v1[1] = c.y; v1[2] = c.z; v1[3] = c.w;
    v1[4] = d.x; v1[5] = d.y; v1[6] = d.z; v1[7] = d.w;
  }
  if (MODE) {
    float dvn = dinv[nc];
    const unsigned* grow = (const unsigned*)(gsum + (size_t)nc * 64);
    uint4 g0 = *(const uint4*)(grow + kb * 4);
    uint4 g1 = *(const uint4*)(grow + 16 + kb * 4);
    unsigned ga[4] = {g0.x, g0.y, g0.z, g0.w};
    unsigned gb[4] = {g1.x, g1.y, g1.z, g1.w};
#pragma unroll
    for (int e = 0; e < 4; e++) {
      v0[2 * e]     = fmaxf(v0[2 * e]     + dvn * bf2f((unsigned short)(ga[e] & 0xffff)), 0.f);
      v0[2 * e + 1] = fmaxf(v0[2 * e + 1] + dvn * bf2f((unsigned short)(ga[e] >> 16)), 0.f);
      v1[2 * e]     = fmaxf(v1[2 * e]     + dvn * bf2f((unsigned short)(gb[e] & 0xffff)), 0.f);
      v1[2 * e + 1] = fmaxf(v1[2 * e + 1] + dvn * bf2f((unsigned short)(gb[e] >> 16)), 0.f);
    }
  }
  bf16x8 ah0, al0, ah1, al1;
#pragma unroll
  for (int e = 0; e < 8; e++) {
    unsigned short h0 = f2bf(v0[e]);
    ah0[e] = (short)h0;
    al0[e] = (short)f2bf(v0[e] - bf2f(h0));
    unsigned short h1 = f2bf(v1[e]);
    ah1[e] = (short)h1;
    al1[e] = (short)f2bf(v1[e] - bf2f(h1));
  }

  f32x4 aC[4], aR[4];
#pragma unroll
  for (int j = 0; j < 4; j++) {
    aC[j] = (f32x4){0.f, 0.f, 0.f, 0.f};
    aR[j] = (f32x4){0.f, 0.f, 0.f, 0.f};
  }
  const bf16x8* WFv = (const bf16x8*)Wf;
#pragma unroll
  for (int j = 0; j < 4; j++) {
    bf16x8 wch0 = WFv[(j)      * 64 + lane];
    bf16x8 wch1 = WFv[(4 + j)  * 64 + lane];
    bf16x8 wcl0 = WFv[(8 + j)  * 64 + lane];
    bf16x8 wcl1 = WFv[(12 + j) * 64 + lane];
    bf16x8 wrh0 = WFv[(16 + j) * 64 + lane];
    bf16x8 wrh1 = WFv[(20 + j) * 64 + lane];
    bf16x8 wrl0 = WFv[(24 + j) * 64 + lane];
    bf16x8 wrl1 = WFv[(28 + j) * 64 + lane];
    f32x4 c = aC[j];
    c = __builtin_amdgcn_mfma_f32_16x16x32_bf16(ah0, wch0, c, 0, 0, 0);
    c = __builtin_amdgcn_mfma_f32_16x16x32_bf16(ah1, wch1, c, 0, 0, 0);
    c = __builtin_amdgcn_mfma_f32_16x16x32_bf16(al0, wch0, c, 0, 0, 0);
    c = __builtin_amdgcn_mfma_f32_16x16x32_bf16(al1, wch1, c, 0, 0, 0);
    c = __builtin_amdgcn_mfma_f32_16x16x32_bf16(ah0, wcl0, c, 0, 0, 0);
    c = __builtin_amdgcn_mfma_f32_16x16x32_bf16(ah1, wcl1, c, 0, 0, 0);
    aC[j] = c;
    f32x4 r = aR[j];
    r = __builtin_amdgcn_mfma_f32_16x16x32_bf16(ah0, wrh0, r, 0, 0, 0);
    r = __builtin_amdgcn_mfma_f32_16x16x32_bf16(ah1, wrh1, r, 0, 0, 0);
    r = __builtin_amdgcn_mfma_f32_16x16x32_bf16(al0, wrh0, r, 0, 0, 0);
    r = __builtin_amdgcn_mfma_f32_16x16x32_bf16(al1, wrh1, r, 0, 0, 0);
    r = __builtin_amdgcn_mfma_f32_16x16x32_bf16(ah0, wrl0, r, 0, 0, 0);
    r = __builtin_amdgcn_mfma_f32_16x16x32_bf16(ah1, wrl1, r, 0, 0, 0);
    aR[j] = r;
  }

  // epilogue: D layout col=lane&15, row=(lane>>4)*4+reg
  float cbv[4], rbv[4];
#pragma unroll
  for (int j = 0; j < 4; j++) {
    cbv[j] = cb[j * 16 + col16];
    rbv[j] = rb[j * 16 + col16];
  }
  int rbase = kb * 4;
#pragma unroll
  for (int r = 0; r < 4; r++) {
    int node = n0 + rbase + r;
    if (node < NN) {
      float dv = dinv[node];
      size_t o = (size_t)node * 64 + col16;
#pragma unroll
      for (int j = 0; j < 4; j++) {
        float hc = dv * aC[j][r];
        unsigned short hb = f2bf(hc);
        hWout[((size_t)((j >> 1) * NPAD + node)) * 32 + (j & 1) * 16 + col16] = hb;  // h-split
        agg[o + j * 16] = aR[j][r] + rbv[j] + cbv[j] + dv * hc;
      }
    }
  }
}

// ---------------- fused: bucket CSR + gptr + encoder + gemm0 (block b = bucket b) ----------------

__global__ __launch_bounds__(256) void k_csr_enc_g0(const int* __restrict__ bcur, const int* __restrict__ colp,
                                                    int* __restrict__ cols, float* __restrict__ dinv,
                                                    int2* __restrict__ rows2,
                                                    const int* __restrict__ batch, int* __restrict__ gptr,
                                                    const float* __restrict__ x, const float* __restrict__ pos,
                                                    const float* __restrict__ encW, const float* __restrict__ encb,
                                                    const unsigned short* __restrict__ Wf,
                                                    const float* __restrict__ cb, const float* __restrict__ rb,
                                                    unsigned short* __restrict__ hWout,
                                                    float* __restrict__ X0, float* __restrict__ agg) {
  __shared__ int hist[64];
  __shared__ int excl[65];
  __shared__ float Ws[16 * 64];
  __shared__ float bs[64];
  int t = threadIdx.x;
  int b = blockIdx.x;

  // folded gptr: graph segment pointers from sorted batch (independent work)
  int tid = b * 256 + t;
  if (tid < NN) {
    int bi = batch[tid];
    int bp = (tid > 0) ? batch[tid - 1] : -1;
    for (int g = bp + 1; g <= bi; g++) gptr[g] = tid;
    if (tid == NN - 1) {
      for (int g = bi + 1; g <= NG; g++) gptr[g] = NN;
    }
  }

  for (int i = t; i < 1024; i += 256) Ws[i] = encW[i];
  if (t < 64) bs[t] = encb[t];

  int base = b * CAP;
  int cnt = bcur[b];
  if (t < 64) hist[t] = 0;
  __syncthreads();
  for (int e = t; e < cnt; e += 256) atomicAdd(&hist[colp[base + e] & 63], 1);
  __syncthreads();
  if (t == 0) {
    int run = 0;
#pragma unroll
    for (int i = 0; i < 64; i++) { excl[i] = run; run += hist[i]; }
    excl[64] = run;
  }
  __syncthreads();
  if (t < 64) {
    int n = b * 64 + t;
    rows2[n] = make_int2(base + excl[t], base + excl[t + 1]);
    if (n < NN) dinv[n] = rsqrtf((float)(hist[t] + 1));  // +1 self-loop
    hist[t] = 0;  // reuse as cursor
  }
  __syncthreads();
  for (int e = t; e < cnt; e += 256) {
    int w = colp[base + e];
    int d = w & 63;
    int r = atomicAdd(&hist[d], 1);
    cols[base + excl[d] + r] = w >> 6;
  }

  // encoder for this bucket's 64 rows (disjoint from cols scatter; barrier below covers both)
  int h = t & 63;
  int nset = t >> 6;
#pragma unroll
  for (int i = 0; i < 16; i++) {
    int n = b * 64 + nset * 16 + i;
    if (n < NN) {
      const float* xr = x + n * 14;
      float acc = bs[h];
#pragma unroll
      for (int f = 0; f < 14; f++) acc += xr[f] * Ws[f * 64 + h];
      acc += pos[n * 2 + 0] * Ws[14 * 64 + h];
      acc += pos[n * 2 + 1] * Ws[15 * 64 + h];
      X0[(size_t)n * 64 + h] = acc;
    }
  }
  __syncthreads();  // X0 + dinv visible block-wide (same CU)

  // gemm0 (mode 0): 4 waves x 16 rows x 64 cols
  gemm_tile<0>(t & 63, b * 64 + (t >> 6) * 16, X0, (const unsigned short*)0, Wf, cb, rb, dinv, hWout, agg);
}

// ---------------- standalone gemm (mode 1), layers 1..4 ----------------

__global__ __launch_bounds__(256) void k_gemm(const float* __restrict__ Xin,
                                              const unsigned short* __restrict__ gsum,
                                              const unsigned short* __restrict__ Wf,
                                              const float* __restrict__ cb, const float* __restrict__ rb,
                                              const float* __restrict__ dinv,
                                              unsigned short* __restrict__ hWout, float* __restrict__ agg) {
  gemm_tile<1>(threadIdx.x & 63, blockIdx.x * 64 + (threadIdx.x >> 6) * 16,
               Xin, gsum, Wf, cb, rb, dinv, hWout, agg);
}

// ---------------- h-split gather core (R6-proven mechanics): one (node, half) per wave ----------------
// lane = (q = lane>>4: edge slot, w = lane&15: h-pair word within 64 B half-row).
// One load instruction covers 4 edges; 8 loads (32 edges) batched in flight.

__device__ __forceinline__ void gather_half(int n, int lane, int w, int q,
                                            const int2* __restrict__ rows2,
                                            const int* __restrict__ cols, const unsigned* __restrict__ hw,
                                            float& a0, float& a1) {
  int2 se = rows2[n];          // one 8-B load for {rowstart, rowend}
  int st = se.x;
  int deg = se.y - se.x;
  a0 = 0.f; a1 = 0.f;
  for (int base2 = 0; base2 < deg; base2 += 64) {
    int cnt = deg - base2;
    if (cnt > 64) cnt = 64;
    int li = lane < cnt ? lane : cnt - 1;
    int colv = cols[st + base2 + li];  // one coalesced load of up to 64 indices
    for (int j = 0; j < cnt; j += 32) {
      int sx[8];
#pragma unroll
      for (int k2 = 0; k2 < 8; k2++) {
        int e = j + 4 * k2 + q;
        int s = __shfl(colv, e, 64);
        sx[k2] = e < cnt ? s : ZR;   // padding -> dedicated zero row (one hot line)
      }
      unsigned ux[8];
#pragma unroll
      for (int k2 = 0; k2 < 8; k2++) ux[k2] = hw[(unsigned)sx[k2] * 16u + (unsigned)w];
#pragma unroll
      for (int k2 = 0; k2 < 8; k2++) {
        a0 += __uint_as_float(ux[k2] << 16);
        a1 += __uint_as_float(ux[k2] & 0xffff0000u);
      }
    }
  }
  a0 += __shfl_down(a0, 32, 64);
  a1 += __shfl_down(a1, 32, 64);
  a0 += __shfl_down(a0, 16, 64);
  a1 += __shfl_down(a1, 16, 64);
}

// ---------------- gather layers 0..3: XCD-pinned halves, interleaved blockIdx ----------------
// half = blockIdx&1: with round-robin blockIdx->XCD, even XCDs stream half 0, odd XCDs half 1 —
// each XCD's compulsory table fill is one 3.2 MB half instead of the full 6.4 MB.

__global__ __launch_bounds__(256, 8) void k_gather(const int2* __restrict__ rows2,
                                                   const int* __restrict__ cols,
                                                   const unsigned short* __restrict__ hWin,
                                                   unsigned short* __restrict__ gsum) {
  int t = threadIdx.x;
  int lane = t & 63;
  int w = lane & 15;
  int q = lane >> 4;
  int half = blockIdx.x & 1;
  int n = __builtin_amdgcn_readfirstlane((blockIdx.x >> 1) * 4 + (t >> 6));
  const unsigned* hw = (const unsigned*)hWin + (size_t)half * NPAD * 16;
  float a0, a1;
  gather_half(n, lane, w, q, rows2, cols, hw, a0, a1);
  if (lane < 16)
    ((unsigned*)gsum)[(unsigned)n * 32u + (unsigned)(half * 16 + w)] =
        (unsigned)f2bf(a0) | ((unsigned)f2bf(a1) << 16);
}

// ---------------- final gather + fused decode -> per-half partials Xo2 ----------------

__global__ __launch_bounds__(256, 8) void k_gather_final(const int2* __restrict__ rows2,
                                                         const int* __restrict__ cols,
                                                         const unsigned short* __restrict__ hWin,
                                                         const float* __restrict__ aggIn, const float* __restrict__ dinv,
                                                         const float* __restrict__ decW, float* __restrict__ Xo2) {
  int t = threadIdx.x;
  int lane = t & 63;
  int w = lane & 15;
  int q = lane >> 4;
  int half = blockIdx.x & 1;
  int n = __builtin_amdgcn_readfirstlane((blockIdx.x >> 1) * 4 + (t >> 6));
  const unsigned* hw = (const unsigned*)hWin + (size_t)half * NPAD * 16;
  float a0, a1;
  gather_half(n, lane, w, q, rows2, cols, hw, a0, a1);
  float dv = dinv[n];
  int hword = half * 16 + w;   // h-pair (2*hword, 2*hword+1)
  float2 ag = ((const float2*)aggIn)[(size_t)n * 32 + hword];  // valid addr for all lanes
  float v = fmaxf(ag.x + dv * a0, 0.f) * decW[hword * 2] + fmaxf(ag.y + dv * a1, 0.f) * decW[hword * 2 + 1];
  v = (lane < 16) ? v : 0.f;  // lanes >=16 hold stale partials -> zero them
#pragma unroll
  for (int off = 8; off > 0; off >>= 1) v += __shfl_down(v, off, 64);
  if (lane == 0) Xo2[(size_t)half * NPAD + n] = v;
}

// ---------------- graph pooling: out[g] = sum over both halves + cnt*decb ----------------

__global__ __launch_bounds__(256) void k_pool(const float* __restrict__ Xo2, const int* __restrict__ gptr,
                                              const float* __restrict__ decb, float* __restrict__ out) {
  __shared__ float part[4];
  int g = blockIdx.x;
  int t = threadIdx.x;
  int st = gptr[g], en = gptr[g + 1];
  float v = 0.f;
  for (int i = st + t; i < en; i += 256) v += Xo2[i] + Xo2[NPAD + i];
#pragma unroll
  for (int off = 32; off > 0; off >>= 1) v += __shfl_down(v, off, 64);
  if ((t & 63) == 0) part[t >> 6] = v;
  __syncthreads();
  if (t == 0) out[g] = part[0] + part[1] + part[2] + part[3] + (float)(en - st) * decb[0];
}

// ---------------- launch: 13 dispatches ----------------

extern "C" void kernel_launch(void* const* d_in, const int* in_sizes, int n_in,
                              void* d_out, int out_size, void* d_ws, size_t ws_size,
                              hipStream_t stream) {
  (void)in_sizes; (void)n_in; (void)out_size; (void)ws_size;
  const float* x     = (const float*)d_in[0];
  const float* pos   = (const float*)d_in[1];
  const int*   ei    = (const int*)d_in[2];
  const int*   batch = (const int*)d_in[3];
  const float* encW  = (const float*)d_in[4];
  const float* encb  = (const float*)d_in[5];
  const float* convW = (const float*)d_in[6];
  const float* convb = (const float*)d_in[7];
  const float* resW  = (const float*)d_in[8];
  const float* resb  = (const float*)d_in[9];
  const float* decW  = (const float*)d_in[10];
  const float* decb  = (const float*)d_in[11];
  float* out = (float*)d_out;

  const int* src = ei;       // edge_index[0]
  const int* dst = ei + NE;  // edge_index[1]

  // workspace layout (4-byte elems)
  float*          ws    = (float*)d_ws;
  float*          dinv  = ws;                                    // [NPAD]
  int2*           rows2 = (int2*)(ws + NPAD);                    // [NPAD] {st,en}
  int*            bcur  = (int*)(ws + 3 * NPAD);                 // [1024]
  int*            gptr  = bcur + 1024;                           // [NG+1]
  float*          Xo2   = (float*)(gptr + 512);                  // [2*NPAD] per-half decode partials
  int*            colp  = (int*)(Xo2 + 2 * NPAD);                // [NBKT*CAP]
  int*            cols  = colp + NBKT * CAP;                     // [NBKT*CAP]
  unsigned short* hWbf  = (unsigned short*)(cols + NBKT * CAP);  // [2][NPAD][32] bf16 h-split
  unsigned short* gsum  = hWbf + (size_t)NPAD * 64;              // [NPAD][64] bf16
  float*          bufA  = (float*)(gsum + (size_t)NPAD * 64);    // [NN*NH]
  float*          bufB  = bufA + NN * NH;                        // [NN*NH]
  unsigned short* Wf    = (unsigned short*)(bufB + NN * NH);     // [32*512] bf16 frag W

  k_prep<<<9, 256, 0, stream>>>(convW, resW, Wf, bcur, hWbf);
  k_bin<<<(NE + 8191) / 8192, 256, 0, stream>>>(src, dst, bcur, colp);
  k_csr_enc_g0<<<NBKT, 256, 0, stream>>>(bcur, colp, cols, dinv, rows2, batch, gptr,
                                         x, pos, encW, encb, Wf, convb, resb,
                                         hWbf, bufA, bufB);
  // layers: XCD-pinned h-split gather -> gsum; gemm mode1 -> hW_{l+1}; agg ping-pong
  float* aggIn = bufB;
  float* aggOut = bufA;
  for (int l = 0; l < 4; l++) {
    k_gather<<<2 * NBH, 256, 0, stream>>>(rows2, cols, hWbf, gsum);
    k_gemm<<<NBKT, 256, 0, stream>>>(aggIn, gsum, Wf, convb, resb, dinv, hWbf, aggOut);
    float* tmp = aggIn; aggIn = aggOut; aggOut = tmp;
  }
  k_gather_final<<<2 * NBH, 256, 0, stream>>>(rows2, cols, hWbf, aggIn, dinv, decW, Xo2);
  k_pool<<<NG, 256, 0, stream>>>(Xo2, gptr, decb, out);
}

// Round 10
// 276.520 us; speedup vs baseline: 2.5068x; 1.1449x over previous
//
#include <hip/hip_runtime.h>

#define NN 50000
#define NE 800000
#define NH 64
#define NG 500
#define NPAD 50176   // 196*256
#define NBKT 782     // ceil(NN/64) 64-node buckets
#define CAP 1536     // padded bucket capacity (max bucket deg ~1130; 4.5+ sigma margin)
#define ZR NN        // dedicated zero row in hWbf (zeroed once in k_prep)

typedef __attribute__((ext_vector_type(8))) short bf16x8;   // 8 bf16 = 4 VGPR (MFMA A/B frag)
typedef __attribute__((ext_vector_type(4))) float f32x4;    // MFMA C/D frag

// fp32 -> bf16 round-to-nearest-even
__device__ __forceinline__ unsigned short f2bf(float f) {
  unsigned x = __float_as_uint(f);
  unsigned r = ((x >> 16) & 1u) + 0x7fffu;
  return (unsigned short)((x + r) >> 16);
}
__device__ __forceinline__ float bf2f(unsigned short u) {
  return __uint_as_float(((unsigned)u) << 16);
}

// ---------------- prep: W fragments + zero bcur/ZR-row ----------------
// Wf fragment convention (16x16x32 bf16): lane = (idx&15) + 16*kb; element e <-> k = s*32 + kb*8 + e.
// fid = mat*16 + part*8 + s*4 + ntile; mat: 0=conv 1=res; part: 0=bf16-hi 1=bf16-lo.

__global__ __launch_bounds__(256) void k_prep(const float* __restrict__ Wc, const float* __restrict__ Wr,
                                              unsigned short* __restrict__ Wf,
                                              int* __restrict__ bcur,
                                              unsigned short* __restrict__ hWbf) {
  if (blockIdx.x == 8) {
    int tt = threadIdx.x;
    for (int i = tt; i < 1024; i += 256) bcur[i] = 0;
    if (tt < 32) ((unsigned*)(hWbf + (size_t)ZR * 64))[tt] = 0u;
    return;
  }
  int t = blockIdx.x * 256 + threadIdx.x;   // 2048 threads = 32 frags * 64 lanes
  int fid = t >> 6;
  int lane = t & 63;
  int ntile = fid & 3, s = (fid >> 2) & 1, part = (fid >> 3) & 1, mat = fid >> 4;
  const float* W = mat ? Wr : Wc;
  int col = ntile * 16 + (lane & 15);
  int k0 = s * 32 + (lane >> 4) * 8;
#pragma unroll
  for (int e = 0; e < 8; e++) {
    float w = W[(k0 + e) * 64 + col];
    unsigned short h = f2bf(w);
    Wf[(size_t)fid * 512 + lane * 8 + e] = part ? f2bf(w - bf2f(h)) : h;
  }
}

// ---------------- binning into padded buckets: colp[b*CAP + r] ----------------

__global__ __launch_bounds__(256) void k_bin(const int* __restrict__ src, const int* __restrict__ dst,
                                             int* __restrict__ bcur, int* __restrict__ colp) {
  __shared__ int hist[NBKT];
  __shared__ int gbase[NBKT];
  int t = threadIdx.x;
  for (int b = t; b < NBKT; b += 256) hist[b] = 0;
  __syncthreads();
  int e0 = blockIdx.x * 8192;
#pragma unroll
  for (int i = 0; i < 32; i++) {
    int e = e0 + i * 256 + t;
    if (e < NE) atomicAdd(&hist[dst[e] >> 6], 1);
  }
  __syncthreads();
  for (int b = t; b < NBKT; b += 256) {
    int c = hist[b];
    gbase[b] = c ? atomicAdd(&bcur[b], c) : 0;
    hist[b] = 0;  // reuse as rank counter
  }
  __syncthreads();
#pragma unroll
  for (int i = 0; i < 32; i++) {
    int e = e0 + i * 256 + t;
    if (e < NE) {
      int s = src[e], d = dst[e];
      int b = d >> 6;
      int r = atomicAdd(&hist[b], 1);
      colp[b * CAP + gbase[b] + r] = (s << 6) | (d & 63);
    }
  }
}

// ---------------- shared gemm tile body (MFMA, LDS-free, split-bf16) ----------------
// MODE 0: X = Xin. MODE 1: X = relu(Xin + dinv[n]*bf2f(gsum[n])).

template <int MODE>
__device__ __forceinline__ void gemm_tile(int lane, int n0,
                                          const float* __restrict__ Xin,
                                          const unsigned short* __restrict__ gsum,
                                          const unsigned short* __restrict__ Wf,
                                          const float* __restrict__ cb, const float* __restrict__ rb,
                                          const float* __restrict__ dinv,
                                          unsigned short* __restrict__ hWout, float* __restrict__ agg) {
  int col16 = lane & 15;
  int kb = lane >> 4;
  int nr = n0 + col16;
  int nc = nr < NN ? nr : NN - 1;   // clamp loads; garbage rows never stored
  const float* xrow = Xin + (size_t)nc * 64;
  float v0[8], v1[8];
  {
    float4 a = *(const float4*)(xrow + kb * 8);
    float4 b4 = *(const float4*)(xrow + kb * 8 + 4);
    float4 c = *(const float4*)(xrow + 32 + kb * 8);
    float4 d = *(const float4*)(xrow + 32 + kb * 8 + 4);
    v0[0] = a.x; v0[1] = a.y; v0[2] = a.z; v0[3] = a.w;
    v0[4] = b4.x; v0[5] = b4.y; v0[6] = b4.z; v0[7] = b4.w;
    v1[0] = c.x; v1[1] = c.y; v1[2] = c.z; v1[3] = c.w;
    v1[4] = d.x; v1[5] = d.y; v1[6] = d.z; v1[7] = d.w;
  }
  if (MODE) {
    float dvn = dinv[nc];
    const unsigned* grow = (const unsigned*)(gsum + (size_t)nc * 64);
    uint4 g0 = *(const uint4*)(grow + kb * 4);
    uint4 g1 = *(const uint4*)(grow + 16 + kb * 4);
    unsigned ga[4] = {g0.x, g0.y, g0.z, g0.w};
    unsigned gb[4] = {g1.x, g1.y, g1.z, g1.w};
#pragma unroll
    for (int e = 0; e < 4; e++) {
      v0[2 * e]     = fmaxf(v0[2 * e]     + dvn * bf2f((unsigned short)(ga[e] & 0xffff)), 0.f);
      v0[2 * e + 1] = fmaxf(v0[2 * e + 1] + dvn * bf2f((unsigned short)(ga[e] >> 16)), 0.f);
      v1[2 * e]     = fmaxf(v1[2 * e]     + dvn * bf2f((unsigned short)(gb[e] & 0xffff)), 0.f);
      v1[2 * e + 1] = fmaxf(v1[2 * e + 1] + dvn * bf2f((unsigned short)(gb[e] >> 16)), 0.f);
    }
  }
  bf16x8 ah0, al0, ah1, al1;
#pragma unroll
  for (int e = 0; e < 8; e++) {
    unsigned short h0 = f2bf(v0[e]);
    ah0[e] = (short)h0;
    al0[e] = (short)f2bf(v0[e] - bf2f(h0));
    unsigned short h1 = f2bf(v1[e]);
    ah1[e] = (short)h1;
    al1[e] = (short)f2bf(v1[e] - bf2f(h1));
  }

  f32x4 aC[4], aR[4];
#pragma unroll
  for (int j = 0; j < 4; j++) {
    aC[j] = (f32x4){0.f, 0.f, 0.f, 0.f};
    aR[j] = (f32x4){0.f, 0.f, 0.f, 0.f};
  }
  const bf16x8* WFv = (const bf16x8*)Wf;
#pragma unroll
  for (int j = 0; j < 4; j++) {
    bf16x8 wch0 = WFv[(j)      * 64 + lane];
    bf16x8 wch1 = WFv[(4 + j)  * 64 + lane];
    bf16x8 wcl0 = WFv[(8 + j)  * 64 + lane];
    bf16x8 wcl1 = WFv[(12 + j) * 64 + lane];
    bf16x8 wrh0 = WFv[(16 + j) * 64 + lane];
    bf16x8 wrh1 = WFv[(20 + j) * 64 + lane];
    bf16x8 wrl0 = WFv[(24 + j) * 64 + lane];
    bf16x8 wrl1 = WFv[(28 + j) * 64 + lane];
    f32x4 c = aC[j];
    c = __builtin_amdgcn_mfma_f32_16x16x32_bf16(ah0, wch0, c, 0, 0, 0);
    c = __builtin_amdgcn_mfma_f32_16x16x32_bf16(ah1, wch1, c, 0, 0, 0);
    c = __builtin_amdgcn_mfma_f32_16x16x32_bf16(al0, wch0, c, 0, 0, 0);
    c = __builtin_amdgcn_mfma_f32_16x16x32_bf16(al1, wch1, c, 0, 0, 0);
    c = __builtin_amdgcn_mfma_f32_16x16x32_bf16(ah0, wcl0, c, 0, 0, 0);
    c = __builtin_amdgcn_mfma_f32_16x16x32_bf16(ah1, wcl1, c, 0, 0, 0);
    aC[j] = c;
    f32x4 r = aR[j];
    r = __builtin_amdgcn_mfma_f32_16x16x32_bf16(ah0, wrh0, r, 0, 0, 0);
    r = __builtin_amdgcn_mfma_f32_16x16x32_bf16(ah1, wrh1, r, 0, 0, 0);
    r = __builtin_amdgcn_mfma_f32_16x16x32_bf16(al0, wrh0, r, 0, 0, 0);
    r = __builtin_amdgcn_mfma_f32_16x16x32_bf16(al1, wrh1, r, 0, 0, 0);
    r = __builtin_amdgcn_mfma_f32_16x16x32_bf16(ah0, wrl0, r, 0, 0, 0);
    r = __builtin_amdgcn_mfma_f32_16x16x32_bf16(ah1, wrl1, r, 0, 0, 0);
    aR[j] = r;
  }

  // epilogue: D layout col=lane&15, row=(lane>>4)*4+reg
  float cbv[4], rbv[4];
#pragma unroll
  for (int j = 0; j < 4; j++) {
    cbv[j] = cb[j * 16 + col16];
    rbv[j] = rb[j * 16 + col16];
  }
  int rbase = kb * 4;
#pragma unroll
  for (int r = 0; r < 4; r++) {
    int node = n0 + rbase + r;
    if (node < NN) {
      float dv = dinv[node];
      size_t o = (size_t)node * 64 + col16;
#pragma unroll
      for (int j = 0; j < 4; j++) {
        float hc = dv * aC[j][r];
        unsigned short hb = f2bf(hc);
        hWout[o + j * 16] = hb;
        agg[o + j * 16] = aR[j][r] + rbv[j] + cbv[j] + dv * hc;
      }
    }
  }
}

// ---------------- fused: bucket CSR + gptr + encoder + gemm0 (block b = bucket b) ----------------

__global__ __launch_bounds__(256) void k_csr_enc_g0(const int* __restrict__ bcur, const int* __restrict__ colp,
                                                    int* __restrict__ cols, float* __restrict__ dinv,
                                                    int2* __restrict__ rows2,
                                                    const int* __restrict__ batch, int* __restrict__ gptr,
                                                    const float* __restrict__ x, const float* __restrict__ pos,
                                                    const float* __restrict__ encW, const float* __restrict__ encb,
                                                    const unsigned short* __restrict__ Wf,
                                                    const float* __restrict__ cb, const float* __restrict__ rb,
                                                    unsigned short* __restrict__ hWout,
                                                    float* __restrict__ X0, float* __restrict__ agg) {
  __shared__ int hist[64];
  __shared__ int excl[65];
  __shared__ float Ws[16 * 64];
  __shared__ float bs[64];
  int t = threadIdx.x;
  int b = blockIdx.x;

  // folded gptr: graph segment pointers from sorted batch (independent work)
  int tid = b * 256 + t;
  if (tid < NN) {
    int bi = batch[tid];
    int bp = (tid > 0) ? batch[tid - 1] : -1;
    for (int g = bp + 1; g <= bi; g++) gptr[g] = tid;
    if (tid == NN - 1) {
      for (int g = bi + 1; g <= NG; g++) gptr[g] = NN;
    }
  }

  for (int i = t; i < 1024; i += 256) Ws[i] = encW[i];
  if (t < 64) bs[t] = encb[t];

  int base = b * CAP;
  int cnt = bcur[b];
  if (t < 64) hist[t] = 0;
  __syncthreads();
  for (int e = t; e < cnt; e += 256) atomicAdd(&hist[colp[base + e] & 63], 1);
  __syncthreads();
  if (t == 0) {
    int run = 0;
#pragma unroll
    for (int i = 0; i < 64; i++) { excl[i] = run; run += hist[i]; }
    excl[64] = run;
  }
  __syncthreads();
  if (t < 64) {
    int n = b * 64 + t;
    rows2[n] = make_int2(base + excl[t], base + excl[t + 1]);  // fused row metadata: 1 load in gather
    if (n < NN) dinv[n] = rsqrtf((float)(hist[t] + 1));  // +1 self-loop
    hist[t] = 0;  // reuse as cursor
  }
  __syncthreads();
  for (int e = t; e < cnt; e += 256) {
    int w = colp[base + e];
    int d = w & 63;
    int r = atomicAdd(&hist[d], 1);
    cols[base + excl[d] + r] = w >> 6;
  }

  // encoder for this bucket's 64 rows (disjoint from cols scatter; barrier below covers both)
  int h = t & 63;
  int nset = t >> 6;
#pragma unroll
  for (int i = 0; i < 16; i++) {
    int n = b * 64 + nset * 16 + i;
    if (n < NN) {
      const float* xr = x + n * 14;
      float acc = bs[h];
#pragma unroll
      for (int f = 0; f < 14; f++) acc += xr[f] * Ws[f * 64 + h];
      acc += pos[n * 2 + 0] * Ws[14 * 64 + h];
      acc += pos[n * 2 + 1] * Ws[15 * 64 + h];
      X0[(size_t)n * 64 + h] = acc;
    }
  }
  __syncthreads();  // X0 + dinv visible block-wide (same CU)

  // gemm0 (mode 0): 4 waves x 16 rows x 64 cols
  gemm_tile<0>(t & 63, b * 64 + (t >> 6) * 16, X0, (const unsigned short*)0, Wf, cb, rb, dinv, hWout, agg);
}

// ---------------- standalone gemm (mode 1), layers 1..4 ----------------

__global__ __launch_bounds__(256) void k_gemm(const float* __restrict__ Xin,
                                              const unsigned short* __restrict__ gsum,
                                              const unsigned short* __restrict__ Wf,
                                              const float* __restrict__ cb, const float* __restrict__ rb,
                                              const float* __restrict__ dinv,
                                              unsigned short* __restrict__ hWout, float* __restrict__ agg) {
  gemm_tile<1>(threadIdx.x & 63, blockIdx.x * 64 + (threadIdx.x >> 6) * 16,
               Xin, gsum, Wf, cb, rb, dinv, hWout, agg);
}

// ---------------- gather core: one node per wave, 16 loads in flight ----------------
// lane = (p = lane>>5, h2 = lane&31): h-pair 2*h2, 2*h2+1 of edge-pair-member p.
// 32-edge groups, 16 batched loads per round: mean deg ~16 -> most rows complete in ONE
// latency round (the 8-deep R5 version took two). (256,4) relaxes the VGPR cap so the
// 16 in-flight loads actually get registers (R3 lesson: tight caps re-serialize loads);
// R4->R5 proved occupancy beyond ~19 waves/CU adds nothing here, so the cap trade is safe.

__device__ __forceinline__ void gather_node(int n, int lane, int h2, int p,
                                            const int2* __restrict__ rows2,
                                            const int* __restrict__ cols, const unsigned* __restrict__ hW32,
                                            float& a0, float& a1) {
  int2 se = rows2[n];          // one 8-B load for {rowstart, rowend}
  int st = se.x;
  int deg = se.y - se.x;
  a0 = 0.f; a1 = 0.f;
  for (int base2 = 0; base2 < deg; base2 += 64) {
    int cnt = deg - base2;
    if (cnt > 64) cnt = 64;
    int li = lane < cnt ? lane : cnt - 1;
    int colv = cols[st + base2 + li];  // one coalesced load of up to 64 indices
    for (int j = 0; j < cnt; j += 32) {
      int sx[16];
#pragma unroll
      for (int k2 = 0; k2 < 16; k2++) {
        int e = j + 2 * k2 + p;
        int s = __shfl(colv, e, 64);
        sx[k2] = e < cnt ? s : ZR;   // padding -> dedicated zero row (one hot line)
      }
      unsigned ux[16];
#pragma unroll
      for (int k2 = 0; k2 < 16; k2++) ux[k2] = hW32[(unsigned)sx[k2] * 32u + (unsigned)h2];
#pragma unroll
      for (int k2 = 0; k2 < 16; k2++) {
        a0 += __uint_as_float(ux[k2] << 16);
        a1 += __uint_as_float(ux[k2] & 0xffff0000u);
      }
    }
  }
  a0 += __shfl_down(a0, 32, 64);
  a1 += __shfl_down(a1, 32, 64);
}

// ---------------- gather layers 0..3: hW -> gsum ----------------

__global__ __launch_bounds__(256, 4) void k_gather(const int2* __restrict__ rows2,
                                                   const int* __restrict__ cols,
                                                   const unsigned short* __restrict__ hWin,
                                                   unsigned short* __restrict__ gsum) {
  int lane = threadIdx.x & 63;
  int h2 = lane & 31;
  int p = lane >> 5;
  int n = __builtin_amdgcn_readfirstlane(blockIdx.x * 4 + (threadIdx.x >> 6));
  float a0, a1;
  gather_node(n, lane, h2, p, rows2, cols, (const unsigned*)hWin, a0, a1);
  if (lane < 32)
    ((unsigned*)gsum)[(unsigned)n * 32u + (unsigned)h2] = (unsigned)f2bf(a0) | ((unsigned)f2bf(a1) << 16);
}

// ---------------- final gather + fused decode -> Xo (plain store; pooling separate) ----------------

__global__ __launch_bounds__(256, 4) void k_gather_final(const int2* __restrict__ rows2,
                                                         const int* __restrict__ cols,
                                                         const unsigned short* __restrict__ hWin,
                                                         const float* __restrict__ aggIn, const float* __restrict__ dinv,
                                                         const float* __restrict__ decW, float* __restrict__ Xo) {
  int lane = threadIdx.x & 63;
  int h2 = lane & 31;
  int p = lane >> 5;
  int n = __builtin_amdgcn_readfirstlane(blockIdx.x * 4 + (threadIdx.x >> 6));
  float a0, a1;
  gather_node(n, lane, h2, p, rows2, cols, (const unsigned*)hWin, a0, a1);
  float dv = dinv[n];
  float2 ag = *(const float2*)(aggIn + (size_t)n * 64 + h2 * 2);  // valid addr for all lanes
  float v = fmaxf(ag.x + dv * a0, 0.f) * decW[h2 * 2] + fmaxf(ag.y + dv * a1, 0.f) * decW[h2 * 2 + 1];
  v = (lane < 32) ? v : 0.f;  // upper half holds stale partials -> zero them
#pragma unroll
  for (int off = 32; off > 0; off >>= 1) v += __shfl_down(v, off, 64);
  if (lane == 0) Xo[n] = v;
}

// ---------------- graph pooling: out[g] = sum Xo[gptr[g]:gptr[g+1]] + cnt*decb ----------------

__global__ __launch_bounds__(256) void k_pool(const float* __restrict__ Xo, const int* __restrict__ gptr,
                                              const float* __restrict__ decb, float* __restrict__ out) {
  __shared__ float part[4];
  int g = blockIdx.x;
  int t = threadIdx.x;
  int st = gptr[g], en = gptr[g + 1];
  float v = 0.f;
  for (int i = st + t; i < en; i += 256) v += Xo[i];
#pragma unroll
  for (int off = 32; off > 0; off >>= 1) v += __shfl_down(v, off, 64);
  if ((t & 63) == 0) part[t >> 6] = v;
  __syncthreads();
  if (t == 0) out[g] = part[0] + part[1] + part[2] + part[3] + (float)(en - st) * decb[0];
}

// ---------------- launch: 13 dispatches ----------------

extern "C" void kernel_launch(void* const* d_in, const int* in_sizes, int n_in,
                              void* d_out, int out_size, void* d_ws, size_t ws_size,
                              hipStream_t stream) {
  (void)in_sizes; (void)n_in; (void)out_size; (void)ws_size;
  const float* x     = (const float*)d_in[0];
  const float* pos   = (const float*)d_in[1];
  const int*   ei    = (const int*)d_in[2];
  const int*   batch = (const int*)d_in[3];
  const float* encW  = (const float*)d_in[4];
  const float* encb  = (const float*)d_in[5];
  const float* convW = (const float*)d_in[6];
  const float* convb = (const float*)d_in[7];
  const float* resW  = (const float*)d_in[8];
  const float* resb  = (const float*)d_in[9];
  const float* decW  = (const float*)d_in[10];
  const float* decb  = (const float*)d_in[11];
  float* out = (float*)d_out;

  const int* src = ei;       // edge_index[0]
  const int* dst = ei + NE;  // edge_index[1]

  // workspace layout (4-byte elems)
  float*          ws    = (float*)d_ws;
  float*          dinv  = ws;                                    // [NPAD]
  int2*           rows2 = (int2*)(ws + NPAD);                    // [NPAD] {st,en}
  int*            bcur  = (int*)(ws + 3 * NPAD);                 // [1024]
  int*            gptr  = bcur + 1024;                           // [NG+1]
  float*          Xo    = (float*)(gptr + 512);                  // [NPAD]
  int*            colp  = (int*)(Xo + NPAD);                     // [NBKT*CAP]
  int*            cols  = colp + NBKT * CAP;                     // [NBKT*CAP]
  unsigned short* hWbf  = (unsigned short*)(cols + NBKT * CAP);  // [NPAD*64] bf16
  unsigned short* gsum  = hWbf + (size_t)NPAD * 64;              // [NPAD*64] bf16
  float*          bufA  = (float*)(gsum + (size_t)NPAD * 64);    // [NN*NH]
  float*          bufB  = bufA + NN * NH;                        // [NN*NH]
  unsigned short* Wf    = (unsigned short*)(bufB + NN * NH);     // [32*512] bf16 frag W

  k_prep<<<9, 256, 0, stream>>>(convW, resW, Wf, bcur, hWbf);
  k_bin<<<(NE + 8191) / 8192, 256, 0, stream>>>(src, dst, bcur, colp);
  k_csr_enc_g0<<<NBKT, 256, 0, stream>>>(bcur, colp, cols, dinv, rows2, batch, gptr,
                                         x, pos, encW, encb, Wf, convb, resb,
                                         hWbf, bufA, bufB);
  // layers: gather hW_l -> gsum; gemm mode1 -> hW_{l+1}, agg ping-pong (B->A->B->A->B)
  float* aggIn = bufB;
  float* aggOut = bufA;
  for (int l = 0; l < 4; l++) {
    k_gather<<<NN / 4, 256, 0, stream>>>(rows2, cols, hWbf, gsum);
    k_gemm<<<NBKT, 256, 0, stream>>>(aggIn, gsum, Wf, convb, resb, dinv, hWbf, aggOut);
    float* tmp = aggIn; aggIn = aggOut; aggOut = tmp;
  }
  k_gather_final<<<NN / 4, 256, 0, stream>>>(rows2, cols, hWbf, aggIn, dinv, decW, Xo);
  k_pool<<<NG, 256, 0, stream>>>(Xo, gptr, decb, out);
}